// Round 16
// baseline (845.726 us; speedup 1.0000x reference)
//
#include <hip/hip_runtime.h>
#include <hip/hip_fp16.h>

// GCN1: ChebConv(K=3) -> global max pool -> MLP(32->1024->512->4)
// fp32 floats, int32 indices (established rounds 0-3).
// Round 16: eliminate k_bcsr (per-node CSR sort, ~25us) — props only need
// bucket-grouped edges, which bscatter2 already produces. Props become
// bucket-streaming: sequential ebuck read + random source gather + LDS
// float-atomic accumulation into accum[128][33] (bank=(cl+f)%32, ~2-way).
// Perfect load balance (no degree tail). combine MFMAs from the LDS tile.

#define NT 256
#define BSHIFT 7
#define BSIZE 128   // nodes per bucket; NBK = ceil(N/128) = 782 <= 1024
#define HB 256      // blocks for hist/scatter passes

typedef _Float16 half8 __attribute__((ext_vector_type(8)));
typedef float f32x4 __attribute__((ext_vector_type(4)));

__device__ __forceinline__ void atomicMaxFloat(float* addr, float val) {
    if (val >= 0.0f) atomicMax((int*)addr, __float_as_int(val));
    else             atomicMin((unsigned int*)addr, __float_as_uint(val));
}

// ---- pass 1: LDS bucket histograms of row and col; per-block counts to global ----
__global__ __launch_bounds__(NT) void k_hist2(const int* __restrict__ row,
                                              const int* __restrict__ col,
                                              int* __restrict__ bhc, int* __restrict__ bhr,
                                              int* __restrict__ blkc, int* __restrict__ blkr,
                                              int E, int NBK, int epb) {
    __shared__ int lhc[1024], lhr[1024];
    int tid = threadIdx.x;
    for (int i = tid; i < 1024; i += NT) { lhc[i] = 0; lhr[i] = 0; }
    __syncthreads();
    int start = blockIdx.x * epb;
    int end = min(start + epb, E);
    for (int e = start + tid; e < end; e += NT) {
        atomicAdd(&lhr[row[e] >> BSHIFT], 1);  // LDS
        atomicAdd(&lhc[col[e] >> BSHIFT], 1);  // LDS
    }
    __syncthreads();
    int base = blockIdx.x * 1024;
    for (int i = tid; i < NBK; i += NT) {
        int vc = lhc[i], vr = lhr[i];
        blkc[base + i] = vc;
        blkr[base + i] = vr;
        if (vc) atomicAdd(&bhc[i], vc);
        if (vr) atomicAdd(&bhr[i], vr);
    }
}

// ---- pass 2: scans of both bucket histograms; inits g; precomputes W fragments ----
__global__ __launch_bounds__(1024) void k_bscan2(const int* __restrict__ bhc,
                                                 const int* __restrict__ bhr,
                                                 int* __restrict__ bbase, int* __restrict__ bcur,
                                                 int* __restrict__ rbase, int* __restrict__ rcur,
                                                 float* __restrict__ g,
                                                 const float* __restrict__ Wc,
                                                 _Float16* __restrict__ wfrag,
                                                 int NBK, int E) {
    __shared__ int s[1024];
    int tid = threadIdx.x;
    for (int i = tid; i < 64 * 32; i += 1024) g[i] = -__builtin_inff();
    // precompute MFMA B-fragments: combo = mat*2+n, frag[combo][lane][j]
    if (tid < 384) {
        int combo = tid >> 6, lane = tid & 63;
        int mat = combo >> 1, n = combo & 1;
        int m = lane & 15, quad = lane >> 4;
        #pragma unroll
        for (int j = 0; j < 8; j++)
            wfrag[(size_t)combo * 512 + lane * 8 + j] =
                (_Float16)Wc[mat * 1024 + (quad * 8 + j) * 32 + n * 16 + m];
    }
    int v = (tid < NBK) ? bhc[tid] : 0;
    s[tid] = v;
    __syncthreads();
    for (int off = 1; off < 1024; off <<= 1) {
        int t = (tid >= off) ? s[tid - off] : 0;
        __syncthreads();
        s[tid] += t;
        __syncthreads();
    }
    if (tid < NBK) { int b = s[tid] - v; bbase[tid] = b; bcur[tid] = b; }
    if (tid == 0) bbase[NBK] = E;
    __syncthreads();
    v = (tid < NBK) ? bhr[tid] : 0;
    s[tid] = v;
    __syncthreads();
    for (int off = 1; off < 1024; off <<= 1) {
        int t = (tid >= off) ? s[tid - off] : 0;
        __syncthreads();
        s[tid] += t;
        __syncthreads();
    }
    if (tid < NBK) { int b = s[tid] - v; rbase[tid] = b; rcur[tid] = b; }
    if (tid == 0) rbase[NBK] = E;
}

// ---- pass 3: single-pass dual scatter (col->ebuck packed int, row->rbuck int) ----
__global__ __launch_bounds__(NT) void k_bscatter2(const int* __restrict__ row,
                                                  const int* __restrict__ col,
                                                  const int* __restrict__ blkc,
                                                  const int* __restrict__ blkr,
                                                  int* __restrict__ bcur, int* __restrict__ rcur,
                                                  int* __restrict__ ebuck, int* __restrict__ rbuck,
                                                  int E, int NBK, int epb) {
    __shared__ int lbasec[1024], lbaser[1024], lhc[1024], lhr[1024];
    int tid = threadIdx.x;
    int base = blockIdx.x * 1024;
    for (int i = tid; i < NBK; i += NT) {
        int vc = blkc[base + i];
        int vr = blkr[base + i];
        lbasec[i] = vc ? atomicAdd(&bcur[i], vc) : 0;
        lbaser[i] = vr ? atomicAdd(&rcur[i], vr) : 0;
        lhc[i] = 0;
        lhr[i] = 0;
    }
    __syncthreads();
    int start = blockIdx.x * epb;
    int end = min(start + epb, E);
    for (int e = start + tid; e < end; e += NT) {
        int r = row[e], c = col[e];
        int bc_ = c >> BSHIFT;
        int li = atomicAdd(&lhc[bc_], 1);  // LDS
        ebuck[lbasec[bc_] + li] = (r << BSHIFT) | (c & (BSIZE - 1));  // r<2^17, fits 24b
        int br_ = r >> BSHIFT;
        int lj = atomicAdd(&lhr[br_], 1);  // LDS
        rbuck[lbaser[br_] + lj] = r;
    }
}

// ---- pass 4: per-row-bucket count -> dis/rdis; fused xh/xsh convert ----
__global__ __launch_bounds__(NT) void k_rcsr_xs(const int* __restrict__ rbase,
                                                const int* __restrict__ rbuck,
                                                const float* __restrict__ x,
                                                float* __restrict__ dis,
                                                float* __restrict__ rdis,
                                                __half* __restrict__ xh,
                                                __half* __restrict__ xsh, int N) {
    __shared__ int cnt[BSIZE];
    __shared__ float sdis[BSIZE];
    int b = blockIdx.x, tid = threadIdx.x;
    int base = rbase[b], endr = rbase[b + 1];
    if (tid < BSIZE) cnt[tid] = 0;
    __syncthreads();
    for (int e = base + tid; e < endr; e += NT)
        atomicAdd(&cnt[rbuck[e] & (BSIZE - 1)], 1);  // LDS
    __syncthreads();
    if (tid < BSIZE) {
        int node = (b << BSHIFT) + tid;
        float d = 0.0f;
        if (node < N) {
            int c = cnt[tid];
            d = (c > 0) ? rsqrtf((float)c) : 0.0f;
            dis[node] = d;
            rdis[node] = (c > 0) ? sqrtf((float)c) : 0.0f;
        }
        sdis[tid] = d;
    }
    __syncthreads();
    int nodebase = b << BSHIFT;
    for (int i4 = tid; i4 < BSIZE * 8; i4 += NT) {  // 128 nodes x 8 float4
        int gnode = nodebase + (i4 >> 3);
        if (gnode >= N) break;
        float4 v = ((const float4*)x)[(size_t)nodebase * 8 + i4];
        float dd = sdis[i4 >> 3];
        float2 o, os;
        ((__half2*)&o)[0] = __floats2half2_rn(v.x, v.y);
        ((__half2*)&o)[1] = __floats2half2_rn(v.z, v.w);
        ((__half2*)&os)[0] = __floats2half2_rn(dd * v.x, dd * v.y);
        ((__half2*)&os)[1] = __floats2half2_rn(dd * v.z, dd * v.w);
        ((float2*)xh)[(size_t)nodebase * 8 + i4] = o;
        ((float2*)xsh)[(size_t)nodebase * 8 + i4] = os;
    }
}

#define GATHER_ACC(SRCBUF)                                                    \
    do {                                                                      \
        int pv = ebuck[e0];                                                   \
        int src = pv >> BSHIFT;                                               \
        int cl = pv & (BSIZE - 1);                                            \
        float4 raw = *(const float4*)((SRCBUF) + (size_t)src * 32 + q * 8);   \
        const __half2* hp = (const __half2*)&raw;                             \
        float2 f0 = __half22float2(hp[0]);                                    \
        float2 f1 = __half22float2(hp[1]);                                    \
        float2 f2 = __half22float2(hp[2]);                                    \
        float2 f3 = __half22float2(hp[3]);                                    \
        float* arow = &accum[cl][q * 8];                                      \
        atomicAdd(&arow[0], f0.x); atomicAdd(&arow[1], f0.y);                 \
        atomicAdd(&arow[2], f1.x); atomicAdd(&arow[3], f1.y);                 \
        atomicAdd(&arow[4], f2.x); atomicAdd(&arow[5], f2.y);                 \
        atomicAdd(&arow[6], f3.x); atomicAdd(&arow[7], f3.y);                 \
    } while (0)

// ---- prop1: bucket-streaming accumulate; xs2 = -dis^2 * sum xs[r] (fp16) ----
__global__ __launch_bounds__(NT) void k_prop1b(const int* __restrict__ bbase,
                                               const int* __restrict__ ebuck,
                                               const float* __restrict__ dis,
                                               const __half* __restrict__ xsh,
                                               __half* __restrict__ xs2h, int N) {
    __shared__ float accum[BSIZE][33];
    int b = blockIdx.x, tid = threadIdx.x;
    for (int i = tid; i < BSIZE * 33; i += NT) ((float*)accum)[i] = 0.0f;
    __syncthreads();
    int s = bbase[b], t = bbase[b + 1];
    int q = tid & 3;
    for (int e0 = s + (tid >> 2); e0 < t; e0 += 64) GATHER_ACC(xsh);
    __syncthreads();
    int nodebase = b << BSHIFT;
    #pragma unroll
    for (int p = 0; p < 2; p++) {  // 2 passes of 64 nodes
        int nl = p * 64 + (tid >> 2);
        int node = nodebase + nl;
        if (node < N) {
            float d = dis[node];
            float sd = -d * d;
            const float* arow = &accum[nl][q * 8];
            float4 ov;
            ((__half2*)&ov)[0] = __floats2half2_rn(sd * arow[0], sd * arow[1]);
            ((__half2*)&ov)[1] = __floats2half2_rn(sd * arow[2], sd * arow[3]);
            ((__half2*)&ov)[2] = __floats2half2_rn(sd * arow[4], sd * arow[5]);
            ((__half2*)&ov)[3] = __floats2half2_rn(sd * arow[6], sd * arow[7]);
            *(float4*)(xs2h + (size_t)node * 32 + q * 8) = ov;
        }
    }
}

// ---- fused prop2 + MFMA combine + segmented max (bucket-streaming) ----
// T1 = xs2 * rdis; T2 = -2*dis*S2 - T0 (S2 in LDS accum). h-tile reuses accum.
__global__ __launch_bounds__(NT) void k_combine_b(
    const int* __restrict__ bbase, const int* __restrict__ ebuck,
    const float* __restrict__ dis, const float* __restrict__ rdis,
    const __half* __restrict__ xs2h, const _Float16* __restrict__ xh,
    const _Float16* __restrict__ wfrag, const float* __restrict__ bc,
    const int* __restrict__ batch, float* __restrict__ g, int N) {
    __shared__ float accum[BSIZE][33];
    __shared__ float sb[32];
    __shared__ int sbatch[BSIZE];
    int b = blockIdx.x, tid = threadIdx.x;
    for (int i = tid; i < BSIZE * 33; i += NT) ((float*)accum)[i] = 0.0f;
    if (tid < 32) sb[tid] = bc[tid];
    int rowbase = b << BSHIFT;
    if (tid < BSIZE) {
        int gr = rowbase + tid;
        sbatch[tid] = (gr < N) ? batch[gr] : -1;
    }
    __syncthreads();
    int s = bbase[b], t = bbase[b + 1];
    int q = tid & 3;
    for (int e0 = s + (tid >> 2); e0 < t; e0 += 64) GATHER_ACC(xs2h);
    __syncthreads();

    // MFMA: wave w handles rows [w*32, w*32+32) = 2 m-tiles
    int wave = tid >> 6, lane = tid & 63, m = lane & 15, quad = lane >> 4;
    const half8* wf = (const half8*)wfrag;
    half8 A0[2], A1[2], A2[2];
    #pragma unroll
    for (int tt = 0; tt < 2; tt++) {
        int lrow = wave * 32 + tt * 16 + m;
        int grow = rowbase + lrow;
        half8 a0 = {}, a1 = {}, a2 = {};
        if (grow < N) {
            size_t off = (size_t)grow * 32 + quad * 8;
            a0 = *(const half8*)(xh + off);
            half8 x2 = *(const half8*)((const _Float16*)xs2h + off);
            float rd = rdis[grow];
            float d2 = -2.0f * dis[grow];
            const float* arow = &accum[lrow][quad * 8];
            #pragma unroll
            for (int j = 0; j < 8; j++) {
                a1[j] = (_Float16)((float)x2[j] * rd);           // T1 = xs2/dis
                a2[j] = (_Float16)(d2 * arow[j] - (float)a0[j]); // T2 = 2*(-dis*S2) - T0
            }
        }
        A0[tt] = a0; A1[tt] = a1; A2[tt] = a2;
    }
    f32x4 acc[2][2];
    #pragma unroll
    for (int tt = 0; tt < 2; tt++)
        #pragma unroll
        for (int n = 0; n < 2; n++) {
            f32x4 c = {0.f, 0.f, 0.f, 0.f};
            c = __builtin_amdgcn_mfma_f32_16x16x32_f16(A0[tt], wf[(0 * 2 + n) * 64 + lane], c, 0, 0, 0);
            c = __builtin_amdgcn_mfma_f32_16x16x32_f16(A1[tt], wf[(1 * 2 + n) * 64 + lane], c, 0, 0, 0);
            c = __builtin_amdgcn_mfma_f32_16x16x32_f16(A2[tt], wf[(2 * 2 + n) * 64 + lane], c, 0, 0, 0);
            acc[tt][n] = c;
        }
    // write h into accum (reuse; each wave writes only its own 32-row region,
    // whose reads completed above within this wave)
    #pragma unroll
    for (int tt = 0; tt < 2; tt++)
        #pragma unroll
        for (int n = 0; n < 2; n++)
            #pragma unroll
            for (int r = 0; r < 4; r++)
                accum[wave * 32 + tt * 16 + quad * 4 + r][n * 16 + m] =
                    acc[tt][n][r] + sb[n * 16 + m];
    __syncthreads();

    // segmented max: 8 groups of 16 rows x 32 features
    int f = tid & 31, sg = tid >> 5;
    int curb = -1;
    float curm = 0.0f;
    for (int j = sg * 16; j < sg * 16 + 16; j++) {
        int bb = sbatch[j];
        if (bb < 0) continue;
        float v = accum[j][f];
        if (bb != curb) {
            if (curb >= 0) atomicMaxFloat(&g[curb * 32 + f], curm);
            curb = bb;
            curm = v;
        } else {
            curm = fmaxf(curm, v);
        }
    }
    if (curb >= 0) atomicMaxFloat(&g[curb * 32 + f], curm);
}

// ---- fused MLP1+MLP2: block (gi,ks) computes h1 chunk in LDS then W2 chunk ----
__global__ __launch_bounds__(NT) void k_mlp12(const float* __restrict__ g,
                                              const float* __restrict__ W1,
                                              const float* __restrict__ b1,
                                              const float* __restrict__ W2,
                                              float* __restrict__ h2acc) {
    __shared__ float sg[32];
    __shared__ float sh[128];
    int gi = blockIdx.x >> 3, ks = blockIdx.x & 7;
    int tid = threadIdx.x;
    if (tid < 32) sg[tid] = g[gi * 32 + tid];
    __syncthreads();
    if (tid < 128) {
        int c = ks * 128 + tid;
        float a = b1[c];
        #pragma unroll
        for (int k = 0; k < 32; k++) a += sg[k] * W1[k * 1024 + c];
        sh[tid] = fmaxf(a, 0.0f);
    }
    __syncthreads();
    const float* w = W2 + (size_t)(ks * 128) * 512;
    float acc0 = 0.0f, acc1 = 0.0f;
    for (int k = 0; k < 128; k++) {
        float h = sh[k];
        acc0 += h * w[k * 512 + tid];
        acc1 += h * w[k * 512 + tid + 256];
    }
    atomicAdd(&h2acc[gi * 512 + tid], acc0);
    atomicAdd(&h2acc[gi * 512 + tid + 256], acc1);
}

// ---- MLP layer 3 (parallel): out[64,4] = relu(h2acc + b2) @ W3 + b3 ----
__global__ __launch_bounds__(NT) void k_mlp3p(const float* __restrict__ h2acc,
                                              const float* __restrict__ b2,
                                              const float* __restrict__ W3,
                                              const float* __restrict__ b3,
                                              float* __restrict__ out) {
    __shared__ float sp[256];
    int gi = blockIdx.x;
    int tid = threadIdx.x;
    int j = tid & 3, slot = tid >> 2;  // 64 K-slots x 4 outputs
    float part = 0.0f;
    #pragma unroll
    for (int kk = 0; kk < 8; kk++) {
        int k = slot * 8 + kk;
        float h = fmaxf(h2acc[gi * 512 + k] + b2[k], 0.0f);
        part += h * W3[k * 4 + j];
    }
    sp[tid] = part;
    __syncthreads();
    for (int s = 32; s >= 1; s >>= 1) {
        if (slot < s) sp[tid] += sp[(slot + s) * 4 + j];
        __syncthreads();
    }
    if (slot == 0) out[gi * 4 + j] = sp[j] + b3[j];
}

extern "C" void kernel_launch(void* const* d_in, const int* in_sizes, int n_in,
                              void* d_out, int out_size, void* d_ws, size_t ws_size,
                              hipStream_t stream) {
    const float* x   = (const float*)d_in[0];
    const int* ei    = (const int*)d_in[1];
    const int* batch = (const int*)d_in[2];
    const float* Wc  = (const float*)d_in[3];
    const float* bc  = (const float*)d_in[4];
    const float* W1  = (const float*)d_in[5];
    const float* b1  = (const float*)d_in[6];
    const float* W2  = (const float*)d_in[7];
    const float* b2  = (const float*)d_in[8];
    const float* W3  = (const float*)d_in[9];
    const float* b3  = (const float*)d_in[10];
    float* out       = (float*)d_out;

    const int N = in_sizes[2];      // 100000
    const int E = in_sizes[1] / 2;  // 1.6M
    const int* row = ei;
    const int* col = ei + E;
    const int NBK = (N + BSIZE - 1) / BSIZE;   // 782 (<= 1024)
    const int epb = (E + HB - 1) / HB;

    // workspace layout (zeroed region first: bhc | bhr | h2acc); no aliasing
    int* iws = (int*)d_ws;
    int* bhc        = iws;                           // 1024
    int* bhr        = bhc + 1024;                    // 1024
    float* h2acc    = (float*)(bhr + 1024);          // 64*512
    int* bbase      = (int*)(h2acc + 64 * 512);      // 1024 (NBK+1)
    int* bcur       = bbase + 1024;                  // 1024
    int* rbase      = bcur + 1024;                   // 1024 (NBK+1)
    int* rcur       = rbase + 1024;                  // 1024
    float* dis      = (float*)(rcur + 1024);         // N
    float* rdis     = dis + N;                       // N
    int* blkc       = (int*)(rdis + N);              // HB*1024
    int* blkr       = blkc + HB * 1024;              // HB*1024
    int* ebuck      = blkr + HB * 1024;              // E
    int* rbuck      = ebuck + E;                     // E
    _Float16* xh    = (_Float16*)(rbuck + E);        // 32N halfs
    _Float16* xsh   = xh + (size_t)N * 32;           // 32N halfs
    _Float16* xs2h  = xsh + (size_t)N * 32;          // 32N halfs
    float* g        = (float*)(xs2h + (size_t)N * 32);  // 64*32
    _Float16* wfrag = (_Float16*)(g + 64 * 32);      // 6*512 halfs

    // one contiguous zero: bhc + bhr + h2acc
    hipMemsetAsync(bhc, 0, sizeof(int) * (1024 + 1024 + 64 * 512), stream);

    k_hist2<<<HB, NT, 0, stream>>>(row, col, bhc, bhr, blkc, blkr, E, NBK, epb);
    k_bscan2<<<1, 1024, 0, stream>>>(bhc, bhr, bbase, bcur, rbase, rcur, g, Wc, wfrag, NBK, E);
    k_bscatter2<<<HB, NT, 0, stream>>>(row, col, blkc, blkr, bcur, rcur, ebuck, rbuck, E, NBK, epb);
    k_rcsr_xs<<<NBK, NT, 0, stream>>>(rbase, rbuck, x, dis, rdis, (__half*)xh, (__half*)xsh, N);
    k_prop1b<<<NBK, NT, 0, stream>>>(bbase, ebuck, dis, (const __half*)xsh, (__half*)xs2h, N);
    k_combine_b<<<NBK, NT, 0, stream>>>(bbase, ebuck, dis, rdis, (const __half*)xs2h, xh, wfrag, bc, batch, g, N);
    k_mlp12<<<512, NT, 0, stream>>>(g, W1, b1, W2, h2acc);
    k_mlp3p<<<64, NT, 0, stream>>>(h2acc, b2, W3, b3, out);
}

// Round 17
// 235.988 us; speedup vs baseline: 3.5838x; 3.5838x over previous
//
#include <hip/hip_runtime.h>
#include <hip/hip_fp16.h>

// GCN1: ChebConv(K=3) -> global max pool -> MLP(32->1024->512->4)
// fp32 floats, int32 indices (established rounds 0-3).
// Round 17: revert round-16's LDS-atomic scatter (345us — LDS float atomics
// with same-address contention are ~10x slower than CSR-sorted register
// accumulation). Back to round-15 structure + self-counting bscatter with
// fixed padded buckets (CAP=5120): k_hist2 and k_bscan2 eliminated; offs
// packed as (base<<9)|indeg; entries in padded layout.

#define NT 256
#define BSHIFT 8
#define BSIZE 256   // nodes per bucket; NBK = ceil(N/256) = 391 <= 512
#define HB 256      // blocks for the scatter pass
#define CAP 5120    // bucket capacity (expected 4096, sigma 64 -> 16-sigma pad)

typedef _Float16 half8 __attribute__((ext_vector_type(8)));
typedef float f32x4 __attribute__((ext_vector_type(4)));

__device__ __forceinline__ void atomicMaxFloat(float* addr, float val) {
    if (val >= 0.0f) atomicMax((int*)addr, __float_as_int(val));
    else             atomicMin((unsigned int*)addr, __float_as_uint(val));
}

#define ACC8(raw)                                        \
    do {                                                 \
        const __half2* hp_ = (const __half2*)&(raw);     \
        float2 f0_ = __half22float2(hp_[0]);             \
        float2 f1_ = __half22float2(hp_[1]);             \
        float2 f2_ = __half22float2(hp_[2]);             \
        float2 f3_ = __half22float2(hp_[3]);             \
        a0 += f0_.x; a1 += f0_.y; a2 += f1_.x; a3 += f1_.y; \
        a4 += f2_.x; a5 += f2_.y; a6 += f3_.x; a7 += f3_.y; \
    } while (0)

// ---- init: g=-inf, wfrag precompute, bucket cursors ----
__global__ __launch_bounds__(512) void k_init(float* __restrict__ g,
                                              const float* __restrict__ Wc,
                                              _Float16* __restrict__ wfrag,
                                              int* __restrict__ bcur,
                                              int* __restrict__ rcur, int NBK) {
    int tid = threadIdx.x;
    for (int i = tid; i < 64 * 32; i += 512) g[i] = -__builtin_inff();
    if (tid < 384) {
        int combo = tid >> 6, lane = tid & 63;
        int mat = combo >> 1, n = combo & 1;
        int m = lane & 15, quad = lane >> 4;
        #pragma unroll
        for (int j = 0; j < 8; j++)
            wfrag[(size_t)combo * 512 + lane * 8 + j] =
                (_Float16)Wc[mat * 1024 + (quad * 8 + j) * 32 + n * 16 + m];
    }
    if (tid < NBK) {
        bcur[tid] = tid * CAP;
        rcur[tid] = tid * CAP;
    }
}

// ---- self-counting dual scatter: col->ebuck packed, row->rbuck ----
__global__ __launch_bounds__(NT) void k_bscatter3(const int* __restrict__ row,
                                                  const int* __restrict__ col,
                                                  int* __restrict__ bcur, int* __restrict__ rcur,
                                                  int* __restrict__ ebuck, int* __restrict__ rbuck,
                                                  int E, int NBK, int epb) {
    __shared__ int lhc[512], lhr[512], lbasec[512], lbaser[512];
    int tid = threadIdx.x;
    for (int i = tid; i < NBK; i += NT) { lhc[i] = 0; lhr[i] = 0; }
    __syncthreads();
    int start = blockIdx.x * epb;
    int end = min(start + epb, E);
    // pass A: count this segment's bucket histograms (segment stays L1/L2-hot)
    for (int e = start + tid; e < end; e += NT) {
        atomicAdd(&lhc[col[e] >> BSHIFT], 1);  // LDS
        atomicAdd(&lhr[row[e] >> BSHIFT], 1);  // LDS
    }
    __syncthreads();
    for (int i = tid; i < NBK; i += NT) {
        int vc = lhc[i], vr = lhr[i];
        lbasec[i] = vc ? atomicAdd(&bcur[i], vc) : 0;
        lbaser[i] = vr ? atomicAdd(&rcur[i], vr) : 0;
        lhc[i] = 0;
        lhr[i] = 0;
    }
    __syncthreads();
    // pass B: scatter
    for (int e = start + tid; e < end; e += NT) {
        int r = row[e], c = col[e];
        int bc_ = c >> BSHIFT;
        int li = atomicAdd(&lhc[bc_], 1);  // LDS
        ebuck[lbasec[bc_] + li] = (r << BSHIFT) | (c & (BSIZE - 1));  // r<2^17: fits
        int br_ = r >> BSHIFT;
        int lj = atomicAdd(&lhr[br_], 1);  // LDS
        rbuck[lbaser[br_] + lj] = r;
    }
}

// ---- per-row-bucket count -> dis/rdis; fused xh/xsh convert ----
__global__ __launch_bounds__(NT) void k_rcsr_xs(const int* __restrict__ rcur,
                                                const int* __restrict__ rbuck,
                                                const float* __restrict__ x,
                                                float* __restrict__ dis,
                                                float* __restrict__ rdis,
                                                __half* __restrict__ xh,
                                                __half* __restrict__ xsh, int N) {
    __shared__ int cnt[BSIZE];
    __shared__ float sdis[BSIZE];
    int b = blockIdx.x, tid = threadIdx.x;
    int base = b * CAP, endr = rcur[b];
    cnt[tid] = 0;
    __syncthreads();
    for (int e = base + tid; e < endr; e += NT)
        atomicAdd(&cnt[rbuck[e] & (BSIZE - 1)], 1);  // LDS
    __syncthreads();
    int node = (b << BSHIFT) + tid;
    float d = 0.0f;
    if (node < N) {
        int c = cnt[tid];
        d = (c > 0) ? rsqrtf((float)c) : 0.0f;
        dis[node] = d;
        rdis[node] = (c > 0) ? sqrtf((float)c) : 0.0f;
    }
    sdis[tid] = d;
    __syncthreads();
    int nodebase = b << BSHIFT;
    for (int i4 = tid; i4 < 2048; i4 += NT) {  // 256 nodes x 8 float4
        int gnode = nodebase + (i4 >> 3);
        if (gnode >= N) break;
        float4 v = ((const float4*)x)[(size_t)nodebase * 8 + i4];
        float dd = sdis[i4 >> 3];
        float2 o, os;
        ((__half2*)&o)[0] = __floats2half2_rn(v.x, v.y);
        ((__half2*)&o)[1] = __floats2half2_rn(v.z, v.w);
        ((__half2*)&os)[0] = __floats2half2_rn(dd * v.x, dd * v.y);
        ((__half2*)&os)[1] = __floats2half2_rn(dd * v.z, dd * v.w);
        ((float2*)xh)[(size_t)nodebase * 8 + i4] = o;
        ((float2*)xsh)[(size_t)nodebase * 8 + i4] = os;
    }
}

// ---- per-col-bucket counting sort -> packed offs + entries (padded layout) ----
__global__ __launch_bounds__(NT) void k_bcsr(const int* __restrict__ bcur,
                                             const int* __restrict__ ebuck,
                                             int* __restrict__ offs,
                                             int* __restrict__ entries, int N) {
    __shared__ int cnt[BSIZE];
    __shared__ int excl[BSIZE];
    int b = blockIdx.x, tid = threadIdx.x;
    int base = b * CAP, endr = bcur[b];
    cnt[tid] = 0;
    __syncthreads();
    for (int e = base + tid; e < endr; e += NT)
        atomicAdd(&cnt[ebuck[e] & (BSIZE - 1)], 1);  // LDS
    __syncthreads();
    int v = cnt[tid];
    excl[tid] = v;
    __syncthreads();
    for (int off = 1; off < BSIZE; off <<= 1) {
        int t = (tid >= off) ? excl[tid - off] : 0;
        __syncthreads();
        excl[tid] += t;
        __syncthreads();
    }
    int ex = excl[tid] - v;  // exclusive prefix
    int node = (b << BSHIFT) + tid;
    if (node < N) offs[node] = ((base + ex) << 9) | v;  // base+ex < 2^21, v < 512
    cnt[tid] = ex;  // reuse as cursor
    __syncthreads();
    for (int e = base + tid; e < endr; e += NT) {
        int pv = ebuck[e];
        int li = atomicAdd(&cnt[pv & (BSIZE - 1)], 1);  // LDS
        entries[base + li] = pv >> BSHIFT;  // src index
    }
}

// ---- prop1: xs2 = -dis^2 * sum xs[r] (fp16). 8 thr/node: 2 edge-halves x 4 q. ----
__global__ __launch_bounds__(NT) void k_prop1(const int* __restrict__ offs,
                                              const int* __restrict__ entries,
                                              const float* __restrict__ dis,
                                              const __half* __restrict__ xsh,
                                              __half* __restrict__ xs2h, int N) {
    int idx = blockIdx.x * blockDim.x + threadIdx.x;
    int node = idx >> 3, sp = (idx >> 2) & 1, q = idx & 3;
    if (node >= N) return;
    int pv = offs[node];
    int s = pv >> 9, deg = pv & 511;
    int mid = s + (deg >> 1), t = s + deg;
    int lo = sp ? mid : s;
    int hi = sp ? t : mid;
    float a0 = 0, a1 = 0, a2 = 0, a3 = 0, a4 = 0, a5 = 0, a6 = 0, a7 = 0;
    for (int e = lo; e < hi; e++) {
        int r = entries[e];
        float4 w = *(const float4*)(xsh + (size_t)r * 32 + q * 8);
        ACC8(w);
    }
    a0 += __shfl_xor(a0, 4); a1 += __shfl_xor(a1, 4);
    a2 += __shfl_xor(a2, 4); a3 += __shfl_xor(a3, 4);
    a4 += __shfl_xor(a4, 4); a5 += __shfl_xor(a5, 4);
    a6 += __shfl_xor(a6, 4); a7 += __shfl_xor(a7, 4);
    if (sp == 0) {
        float d = dis[node];
        float sd = -d * d;  // xs2 = dis * tx1 = -dis^2 * S
        float4 ov;
        ((__half2*)&ov)[0] = __floats2half2_rn(sd * a0, sd * a1);
        ((__half2*)&ov)[1] = __floats2half2_rn(sd * a2, sd * a3);
        ((__half2*)&ov)[2] = __floats2half2_rn(sd * a4, sd * a5);
        ((__half2*)&ov)[3] = __floats2half2_rn(sd * a6, sd * a7);
        *(float4*)(xs2h + (size_t)node * 32 + q * 8) = ov;
    }
}

// ---- fused prop2 + MFMA combine + segmented max ----
// T1 reconstructed as xs2 * rdis (rdis = sqrt(deg) = 1/dis; 0 if deg=0).
__global__ __launch_bounds__(NT) void k_combine_f(
    const int* __restrict__ offs, const int* __restrict__ entries,
    const float* __restrict__ dis, const float* __restrict__ rdis,
    const __half* __restrict__ xs2h, const _Float16* __restrict__ xh,
    const _Float16* __restrict__ wfrag, const float* __restrict__ bc,
    const int* __restrict__ batch, float* __restrict__ g, int N) {
    __shared__ float sb[32];
    __shared__ float sp2[64][33];
    __shared__ float hs[64][33];
    __shared__ int sbatch[64];

    int tid = threadIdx.x;
    if (tid < 32) sb[tid] = bc[tid];
    int rowbase = blockIdx.x * 64;
    if (tid >= 64 && tid < 128) {
        int gr = rowbase + tid - 64;
        sbatch[tid - 64] = (gr < N) ? batch[gr] : -1;
    }

    // phase 1: gather prop2 into sp2 (4 thr/node)
    int node_l = tid >> 2, q = tid & 3;
    int gnode = rowbase + node_l;
    if (gnode < N) {
        int pv = offs[gnode];
        int s = pv >> 9, t = s + (pv & 511);
        float a0 = 0, a1 = 0, a2 = 0, a3 = 0, a4 = 0, a5 = 0, a6 = 0, a7 = 0;
        for (int e = s; e < t; e++) {
            int r = entries[e];
            float4 w = *(const float4*)(xs2h + (size_t)r * 32 + q * 8);
            ACC8(w);
        }
        float sc = -dis[gnode];
        float* p = &sp2[node_l][q * 8];
        p[0] = sc * a0; p[1] = sc * a1; p[2] = sc * a2; p[3] = sc * a3;
        p[4] = sc * a4; p[5] = sc * a5; p[6] = sc * a6; p[7] = sc * a7;
    }
    __syncthreads();

    // phase 2: MFMA with precomputed B-fragments
    int wave = tid >> 6;
    int lane = tid & 63;
    int m = lane & 15;
    int quad = lane >> 4;
    int grow = rowbase + wave * 16 + m;

    half8 a0 = {}, a1 = {}, a2 = {};
    if (grow < N) {
        size_t off = (size_t)grow * 32 + quad * 8;
        a0 = *(const half8*)(xh + off);
        half8 x2 = *(const half8*)((const _Float16*)xs2h + off);
        float rd = rdis[grow];
        const float* p = &sp2[wave * 16 + m][quad * 8];
        #pragma unroll
        for (int j = 0; j < 8; j++) {
            a1[j] = (_Float16)((float)x2[j] * rd);          // T1 = xs2 / dis
            a2[j] = (_Float16)(2.0f * p[j] - (float)a0[j]); // T2 = 2*P2 - T0
        }
    }

    const half8* wf = (const half8*)wfrag;
    f32x4 acc[2];
    #pragma unroll
    for (int n = 0; n < 2; n++) {
        f32x4 c = {0.f, 0.f, 0.f, 0.f};
        c = __builtin_amdgcn_mfma_f32_16x16x32_f16(a0, wf[(0 * 2 + n) * 64 + lane], c, 0, 0, 0);
        c = __builtin_amdgcn_mfma_f32_16x16x32_f16(a1, wf[(1 * 2 + n) * 64 + lane], c, 0, 0, 0);
        c = __builtin_amdgcn_mfma_f32_16x16x32_f16(a2, wf[(2 * 2 + n) * 64 + lane], c, 0, 0, 0);
        acc[n] = c;
    }

    #pragma unroll
    for (int n = 0; n < 2; n++)
        #pragma unroll
        for (int r = 0; r < 4; r++)
            hs[wave * 16 + quad * 4 + r][n * 16 + m] = acc[n][r] + sb[n * 16 + m];
    __syncthreads();

    // phase 3: segmented max
    int f = tid & 31, s = tid >> 5;
    int curb = -1;
    float curm = 0.0f;
    for (int j = s * 8; j < s * 8 + 8; j++) {
        int b = sbatch[j];
        if (b < 0) continue;
        float v = hs[j][f];
        if (b != curb) {
            if (curb >= 0) atomicMaxFloat(&g[curb * 32 + f], curm);
            curb = b;
            curm = v;
        } else {
            curm = fmaxf(curm, v);
        }
    }
    if (curb >= 0) atomicMaxFloat(&g[curb * 32 + f], curm);
}

// ---- fused MLP1+MLP2: block (gi,ks) computes h1 chunk in LDS then W2 chunk ----
__global__ __launch_bounds__(NT) void k_mlp12(const float* __restrict__ g,
                                              const float* __restrict__ W1,
                                              const float* __restrict__ b1,
                                              const float* __restrict__ W2,
                                              float* __restrict__ h2acc) {
    __shared__ float sg[32];
    __shared__ float sh[128];
    int gi = blockIdx.x >> 3, ks = blockIdx.x & 7;
    int tid = threadIdx.x;
    if (tid < 32) sg[tid] = g[gi * 32 + tid];
    __syncthreads();
    if (tid < 128) {
        int c = ks * 128 + tid;
        float a = b1[c];
        #pragma unroll
        for (int k = 0; k < 32; k++) a += sg[k] * W1[k * 1024 + c];
        sh[tid] = fmaxf(a, 0.0f);
    }
    __syncthreads();
    const float* w = W2 + (size_t)(ks * 128) * 512;
    float acc0 = 0.0f, acc1 = 0.0f;
    for (int k = 0; k < 128; k++) {
        float h = sh[k];
        acc0 += h * w[k * 512 + tid];
        acc1 += h * w[k * 512 + tid + 256];
    }
    atomicAdd(&h2acc[gi * 512 + tid], acc0);
    atomicAdd(&h2acc[gi * 512 + tid + 256], acc1);
}

// ---- MLP layer 3 (parallel): out[64,4] = relu(h2acc + b2) @ W3 + b3 ----
__global__ __launch_bounds__(NT) void k_mlp3p(const float* __restrict__ h2acc,
                                              const float* __restrict__ b2,
                                              const float* __restrict__ W3,
                                              const float* __restrict__ b3,
                                              float* __restrict__ out) {
    __shared__ float sp[256];
    int gi = blockIdx.x;
    int tid = threadIdx.x;
    int j = tid & 3, slot = tid >> 2;  // 64 K-slots x 4 outputs
    float part = 0.0f;
    #pragma unroll
    for (int kk = 0; kk < 8; kk++) {
        int k = slot * 8 + kk;
        float h = fmaxf(h2acc[gi * 512 + k] + b2[k], 0.0f);
        part += h * W3[k * 4 + j];
    }
    sp[tid] = part;
    __syncthreads();
    for (int s = 32; s >= 1; s >>= 1) {
        if (slot < s) sp[tid] += sp[(slot + s) * 4 + j];
        __syncthreads();
    }
    if (slot == 0) out[gi * 4 + j] = sp[j] + b3[j];
}

extern "C" void kernel_launch(void* const* d_in, const int* in_sizes, int n_in,
                              void* d_out, int out_size, void* d_ws, size_t ws_size,
                              hipStream_t stream) {
    const float* x   = (const float*)d_in[0];
    const int* ei    = (const int*)d_in[1];
    const int* batch = (const int*)d_in[2];
    const float* Wc  = (const float*)d_in[3];
    const float* bc  = (const float*)d_in[4];
    const float* W1  = (const float*)d_in[5];
    const float* b1  = (const float*)d_in[6];
    const float* W2  = (const float*)d_in[7];
    const float* b2  = (const float*)d_in[8];
    const float* W3  = (const float*)d_in[9];
    const float* b3  = (const float*)d_in[10];
    float* out       = (float*)d_out;

    const int N = in_sizes[2];      // 100000
    const int E = in_sizes[1] / 2;  // 1.6M
    const int* row = ei;
    const int* col = ei + E;
    const int NBK = (N + BSIZE - 1) / BSIZE;   // 391 (<= 512)
    const int epb = (E + HB - 1) / HB;
    const size_t PADE = (size_t)NBK * CAP;     // padded edge capacity

    // workspace layout
    float* h2acc    = (float*)d_ws;                  // 64*512 (memset)
    int* bcur       = (int*)(h2acc + 64 * 512);      // 512
    int* rcur       = bcur + 512;                    // 512
    float* dis      = (float*)(rcur + 512);          // N
    float* rdis     = dis + N;                       // N
    int* offs       = (int*)(rdis + N);              // N (+4 pad)
    int* ebuck      = offs + N + 4;                  // PADE
    int* rbuck      = ebuck + PADE;                  // PADE
    int* entries    = rbuck + PADE;                  // PADE
    _Float16* xh    = (_Float16*)(entries + PADE);   // 32N halfs
    _Float16* xsh   = xh + (size_t)N * 32;           // 32N halfs
    _Float16* xs2h  = xsh + (size_t)N * 32;          // 32N halfs
    float* g        = (float*)(xs2h + (size_t)N * 32);  // 64*32
    _Float16* wfrag = (_Float16*)(g + 64 * 32);      // 6*512 halfs

    hipMemsetAsync(h2acc, 0, sizeof(float) * 64 * 512, stream);

    k_init<<<1, 512, 0, stream>>>(g, Wc, wfrag, bcur, rcur, NBK);
    k_bscatter3<<<HB, NT, 0, stream>>>(row, col, bcur, rcur, ebuck, rbuck, E, NBK, epb);
    k_rcsr_xs<<<NBK, NT, 0, stream>>>(rcur, rbuck, x, dis, rdis, (__half*)xh, (__half*)xsh, N);
    k_bcsr<<<NBK, NT, 0, stream>>>(bcur, ebuck, offs, entries, N);
    k_prop1<<<((size_t)N * 8 + NT - 1) / NT, NT, 0, stream>>>(offs, entries, dis, (const __half*)xsh, (__half*)xs2h, N);
    k_combine_f<<<(N + 63) / 64, NT, 0, stream>>>(offs, entries, dis, rdis, (const __half*)xs2h, xh, wfrag, bc, batch, g, N);
    k_mlp12<<<512, NT, 0, stream>>>(g, W1, b1, W2, h2acc);
    k_mlp3p<<<64, NT, 0, stream>>>(h2acc, b2, W3, b3, out);
}

// Round 18
// 228.584 us; speedup vs baseline: 3.6998x; 1.0324x over previous
//
#include <hip/hip_runtime.h>
#include <hip/hip_fp16.h>

// GCN1: ChebConv(K=3) -> global max pool -> MLP(32->1024->512->4)
// fp32 floats, int32 indices (established rounds 0-3).
// Round 18: (a) counting sort -> 1024 bins (node x src-range): entry lists
// become src-range-major (1.6MB ranges fit per-XCD L2 -> kills gather
// thrash in prop1+combine), 4x less LDS-atomic contention; (b) fuse
// rcsr_xs+bcsr into k_prep; (c) rbuck stored as uint8 (only low 8 bits used).

#define NT 256
#define BSHIFT 8
#define BSIZE 256   // nodes per bucket; NBK = ceil(N/256) = 391 <= 512
#define HB 256      // blocks for the scatter pass
#define CAP 5120    // bucket capacity (expected 4096, 16-sigma pad)

typedef _Float16 half8 __attribute__((ext_vector_type(8)));
typedef float f32x4 __attribute__((ext_vector_type(4)));

__device__ __forceinline__ void atomicMaxFloat(float* addr, float val) {
    if (val >= 0.0f) atomicMax((int*)addr, __float_as_int(val));
    else             atomicMin((unsigned int*)addr, __float_as_uint(val));
}

#define ACC8(raw)                                        \
    do {                                                 \
        const __half2* hp_ = (const __half2*)&(raw);     \
        float2 f0_ = __half22float2(hp_[0]);             \
        float2 f1_ = __half22float2(hp_[1]);             \
        float2 f2_ = __half22float2(hp_[2]);             \
        float2 f3_ = __half22float2(hp_[3]);             \
        a0 += f0_.x; a1 += f0_.y; a2 += f1_.x; a3 += f1_.y; \
        a4 += f2_.x; a5 += f2_.y; a6 += f3_.x; a7 += f3_.y; \
    } while (0)

// ---- init: g=-inf, wfrag precompute, bucket cursors ----
__global__ __launch_bounds__(512) void k_init(float* __restrict__ g,
                                              const float* __restrict__ Wc,
                                              _Float16* __restrict__ wfrag,
                                              int* __restrict__ bcur,
                                              int* __restrict__ rcur, int NBK) {
    int tid = threadIdx.x;
    for (int i = tid; i < 64 * 32; i += 512) g[i] = -__builtin_inff();
    if (tid < 384) {
        int combo = tid >> 6, lane = tid & 63;
        int mat = combo >> 1, n = combo & 1;
        int m = lane & 15, quad = lane >> 4;
        #pragma unroll
        for (int j = 0; j < 8; j++)
            wfrag[(size_t)combo * 512 + lane * 8 + j] =
                (_Float16)Wc[mat * 1024 + (quad * 8 + j) * 32 + n * 16 + m];
    }
    if (tid < NBK) {
        bcur[tid] = tid * CAP;
        rcur[tid] = tid * CAP;
    }
}

// ---- self-counting dual scatter: col->ebuck packed int, row->rbuck uint8 ----
__global__ __launch_bounds__(NT) void k_bscatter3(const int* __restrict__ row,
                                                  const int* __restrict__ col,
                                                  int* __restrict__ bcur, int* __restrict__ rcur,
                                                  int* __restrict__ ebuck,
                                                  unsigned char* __restrict__ rbuck,
                                                  int E, int NBK, int epb) {
    __shared__ int lhc[512], lhr[512], lbasec[512], lbaser[512];
    int tid = threadIdx.x;
    for (int i = tid; i < NBK; i += NT) { lhc[i] = 0; lhr[i] = 0; }
    __syncthreads();
    int start = blockIdx.x * epb;
    int end = min(start + epb, E);
    // pass A: count this segment's bucket histograms (segment stays L1/L2-hot)
    for (int e = start + tid; e < end; e += NT) {
        atomicAdd(&lhc[col[e] >> BSHIFT], 1);  // LDS
        atomicAdd(&lhr[row[e] >> BSHIFT], 1);  // LDS
    }
    __syncthreads();
    for (int i = tid; i < NBK; i += NT) {
        int vc = lhc[i], vr = lhr[i];
        lbasec[i] = vc ? atomicAdd(&bcur[i], vc) : 0;
        lbaser[i] = vr ? atomicAdd(&rcur[i], vr) : 0;
        lhc[i] = 0;
        lhr[i] = 0;
    }
    __syncthreads();
    // pass B: scatter
    for (int e = start + tid; e < end; e += NT) {
        int r = row[e], c = col[e];
        int bc_ = c >> BSHIFT;
        int li = atomicAdd(&lhc[bc_], 1);  // LDS
        ebuck[lbasec[bc_] + li] = (r << BSHIFT) | (c & (BSIZE - 1));  // r<2^17: fits
        int br_ = r >> BSHIFT;
        int lj = atomicAdd(&lhr[br_], 1);  // LDS
        rbuck[lbaser[br_] + lj] = (unsigned char)(r & (BSIZE - 1));
    }
}

// ---- fused prep: out-degree -> dis/rdis; x->xh/xsh; 1024-bin sort of ebuck ----
// bin = (cl<<2) | (src>>15): each node's entry list is src-range-major,
// ranges of 32768 nodes (1.6MB fp16 rows -> per-XCD L2 resident).
__global__ __launch_bounds__(NT) void k_prep(
    const int* __restrict__ rcur, const unsigned char* __restrict__ rbuck,
    const int* __restrict__ bcur, const int* __restrict__ ebuck,
    const float* __restrict__ x,
    float* __restrict__ dis, float* __restrict__ rdis,
    __half* __restrict__ xh, __half* __restrict__ xsh,
    int* __restrict__ offs, int* __restrict__ entries, int N) {
    __shared__ int cnt[1024];
    __shared__ int tsum[256];
    __shared__ float sdis[256];
    int b = blockIdx.x, tid = threadIdx.x;
    int rbase = b * CAP, rend = rcur[b];
    int ebase = b * CAP, eend = bcur[b];
    cnt[tid] = 0; cnt[tid + 256] = 0; cnt[tid + 512] = 0; cnt[tid + 768] = 0;
    __syncthreads();
    // out-degree count from rbuck (uint8 bucket-local ids)
    for (int e = rbase + tid; e < rend; e += NT)
        atomicAdd(&cnt[rbuck[e]], 1);  // LDS, bins 0..255
    __syncthreads();
    int dcount = cnt[tid];
    int node = (b << BSHIFT) + tid;
    float d = (dcount > 0) ? rsqrtf((float)dcount) : 0.0f;
    if (node < N) {
        dis[node] = d;
        rdis[node] = (dcount > 0) ? sqrtf((float)dcount) : 0.0f;
    }
    sdis[tid] = d;
    __syncthreads();
    cnt[tid] = 0; cnt[tid + 256] = 0; cnt[tid + 512] = 0; cnt[tid + 768] = 0;
    __syncthreads();
    // count 1024 bins
    for (int e = ebase + tid; e < eend; e += NT) {
        int pv = ebuck[e];
        atomicAdd(&cnt[((pv & (BSIZE - 1)) << 2) | ((pv >> BSHIFT) >> 15)], 1);
    }
    __syncthreads();
    // per-node (4-bin) sums + 256-wide scan
    int s0 = cnt[tid * 4], s1 = cnt[tid * 4 + 1], s2 = cnt[tid * 4 + 2], s3 = cnt[tid * 4 + 3];
    int tot = s0 + s1 + s2 + s3;
    tsum[tid] = tot;
    __syncthreads();
    for (int off = 1; off < 256; off <<= 1) {
        int t = (tid >= off) ? tsum[tid - off] : 0;
        __syncthreads();
        tsum[tid] += t;
        __syncthreads();
    }
    int excl = tsum[tid] - tot;
    if (node < N) offs[node] = ((ebase + excl) << 9) | tot;  // base < 2^21, tot < 512
    cnt[tid * 4]     = ebase + excl;
    cnt[tid * 4 + 1] = ebase + excl + s0;
    cnt[tid * 4 + 2] = ebase + excl + s0 + s1;
    cnt[tid * 4 + 3] = ebase + excl + s0 + s1 + s2;
    __syncthreads();
    // scatter (absolute positions in cursors)
    for (int e = ebase + tid; e < eend; e += NT) {
        int pv = ebuck[e];
        int src = pv >> BSHIFT;
        int li = atomicAdd(&cnt[((pv & (BSIZE - 1)) << 2) | (src >> 15)], 1);  // LDS
        entries[li] = src;
    }
    // x -> xh (fp16) and xsh (dis-scaled fp16)
    int nodebase = b << BSHIFT;
    for (int i4 = tid; i4 < 2048; i4 += NT) {  // 256 nodes x 8 float4
        int gnode = nodebase + (i4 >> 3);
        if (gnode >= N) break;
        float4 v = ((const float4*)x)[(size_t)nodebase * 8 + i4];
        float dd = sdis[i4 >> 3];
        float2 o, os;
        ((__half2*)&o)[0] = __floats2half2_rn(v.x, v.y);
        ((__half2*)&o)[1] = __floats2half2_rn(v.z, v.w);
        ((__half2*)&os)[0] = __floats2half2_rn(dd * v.x, dd * v.y);
        ((__half2*)&os)[1] = __floats2half2_rn(dd * v.z, dd * v.w);
        ((float2*)xh)[(size_t)nodebase * 8 + i4] = o;
        ((float2*)xsh)[(size_t)nodebase * 8 + i4] = os;
    }
}

// ---- prop1: xs2 = -dis^2 * sum xs[r] (fp16). 8 thr/node: 2 edge-halves x 4 q. ----
__global__ __launch_bounds__(NT) void k_prop1(const int* __restrict__ offs,
                                              const int* __restrict__ entries,
                                              const float* __restrict__ dis,
                                              const __half* __restrict__ xsh,
                                              __half* __restrict__ xs2h, int N) {
    int idx = blockIdx.x * blockDim.x + threadIdx.x;
    int node = idx >> 3, sp = (idx >> 2) & 1, q = idx & 3;
    if (node >= N) return;
    int pv = offs[node];
    int s = pv >> 9, deg = pv & 511;
    int mid = s + (deg >> 1), t = s + deg;
    int lo = sp ? mid : s;
    int hi = sp ? t : mid;
    float a0 = 0, a1 = 0, a2 = 0, a3 = 0, a4 = 0, a5 = 0, a6 = 0, a7 = 0;
    for (int e = lo; e < hi; e++) {
        int r = entries[e];
        float4 w = *(const float4*)(xsh + (size_t)r * 32 + q * 8);
        ACC8(w);
    }
    a0 += __shfl_xor(a0, 4); a1 += __shfl_xor(a1, 4);
    a2 += __shfl_xor(a2, 4); a3 += __shfl_xor(a3, 4);
    a4 += __shfl_xor(a4, 4); a5 += __shfl_xor(a5, 4);
    a6 += __shfl_xor(a6, 4); a7 += __shfl_xor(a7, 4);
    if (sp == 0) {
        float d = dis[node];
        float sd = -d * d;  // xs2 = dis * tx1 = -dis^2 * S
        float4 ov;
        ((__half2*)&ov)[0] = __floats2half2_rn(sd * a0, sd * a1);
        ((__half2*)&ov)[1] = __floats2half2_rn(sd * a2, sd * a3);
        ((__half2*)&ov)[2] = __floats2half2_rn(sd * a4, sd * a5);
        ((__half2*)&ov)[3] = __floats2half2_rn(sd * a6, sd * a7);
        *(float4*)(xs2h + (size_t)node * 32 + q * 8) = ov;
    }
}

// ---- fused prop2 + MFMA combine + segmented max ----
// T1 reconstructed as xs2 * rdis (rdis = sqrt(deg) = 1/dis; 0 if deg=0).
__global__ __launch_bounds__(NT) void k_combine_f(
    const int* __restrict__ offs, const int* __restrict__ entries,
    const float* __restrict__ dis, const float* __restrict__ rdis,
    const __half* __restrict__ xs2h, const _Float16* __restrict__ xh,
    const _Float16* __restrict__ wfrag, const float* __restrict__ bc,
    const int* __restrict__ batch, float* __restrict__ g, int N) {
    __shared__ float sb[32];
    __shared__ float sp2[64][33];
    __shared__ float hs[64][33];
    __shared__ int sbatch[64];

    int tid = threadIdx.x;
    if (tid < 32) sb[tid] = bc[tid];
    int rowbase = blockIdx.x * 64;
    if (tid >= 64 && tid < 128) {
        int gr = rowbase + tid - 64;
        sbatch[tid - 64] = (gr < N) ? batch[gr] : -1;
    }

    // phase 1: gather prop2 into sp2 (4 thr/node)
    int node_l = tid >> 2, q = tid & 3;
    int gnode = rowbase + node_l;
    if (gnode < N) {
        int pv = offs[gnode];
        int s = pv >> 9, t = s + (pv & 511);
        float a0 = 0, a1 = 0, a2 = 0, a3 = 0, a4 = 0, a5 = 0, a6 = 0, a7 = 0;
        for (int e = s; e < t; e++) {
            int r = entries[e];
            float4 w = *(const float4*)(xs2h + (size_t)r * 32 + q * 8);
            ACC8(w);
        }
        float sc = -dis[gnode];
        float* p = &sp2[node_l][q * 8];
        p[0] = sc * a0; p[1] = sc * a1; p[2] = sc * a2; p[3] = sc * a3;
        p[4] = sc * a4; p[5] = sc * a5; p[6] = sc * a6; p[7] = sc * a7;
    }
    __syncthreads();

    // phase 2: MFMA with precomputed B-fragments
    int wave = tid >> 6;
    int lane = tid & 63;
    int m = lane & 15;
    int quad = lane >> 4;
    int grow = rowbase + wave * 16 + m;

    half8 a0 = {}, a1 = {}, a2 = {};
    if (grow < N) {
        size_t off = (size_t)grow * 32 + quad * 8;
        a0 = *(const half8*)(xh + off);
        half8 x2 = *(const half8*)((const _Float16*)xs2h + off);
        float rd = rdis[grow];
        const float* p = &sp2[wave * 16 + m][quad * 8];
        #pragma unroll
        for (int j = 0; j < 8; j++) {
            a1[j] = (_Float16)((float)x2[j] * rd);          // T1 = xs2 / dis
            a2[j] = (_Float16)(2.0f * p[j] - (float)a0[j]); // T2 = 2*P2 - T0
        }
    }

    const half8* wf = (const half8*)wfrag;
    f32x4 acc[2];
    #pragma unroll
    for (int n = 0; n < 2; n++) {
        f32x4 c = {0.f, 0.f, 0.f, 0.f};
        c = __builtin_amdgcn_mfma_f32_16x16x32_f16(a0, wf[(0 * 2 + n) * 64 + lane], c, 0, 0, 0);
        c = __builtin_amdgcn_mfma_f32_16x16x32_f16(a1, wf[(1 * 2 + n) * 64 + lane], c, 0, 0, 0);
        c = __builtin_amdgcn_mfma_f32_16x16x32_f16(a2, wf[(2 * 2 + n) * 64 + lane], c, 0, 0, 0);
        acc[n] = c;
    }

    #pragma unroll
    for (int n = 0; n < 2; n++)
        #pragma unroll
        for (int r = 0; r < 4; r++)
            hs[wave * 16 + quad * 4 + r][n * 16 + m] = acc[n][r] + sb[n * 16 + m];
    __syncthreads();

    // phase 3: segmented max
    int f = tid & 31, s = tid >> 5;
    int curb = -1;
    float curm = 0.0f;
    for (int j = s * 8; j < s * 8 + 8; j++) {
        int b = sbatch[j];
        if (b < 0) continue;
        float v = hs[j][f];
        if (b != curb) {
            if (curb >= 0) atomicMaxFloat(&g[curb * 32 + f], curm);
            curb = b;
            curm = v;
        } else {
            curm = fmaxf(curm, v);
        }
    }
    if (curb >= 0) atomicMaxFloat(&g[curb * 32 + f], curm);
}

// ---- fused MLP1+MLP2: block (gi,ks) computes h1 chunk in LDS then W2 chunk ----
__global__ __launch_bounds__(NT) void k_mlp12(const float* __restrict__ g,
                                              const float* __restrict__ W1,
                                              const float* __restrict__ b1,
                                              const float* __restrict__ W2,
                                              float* __restrict__ h2acc) {
    __shared__ float sg[32];
    __shared__ float sh[128];
    int gi = blockIdx.x >> 3, ks = blockIdx.x & 7;
    int tid = threadIdx.x;
    if (tid < 32) sg[tid] = g[gi * 32 + tid];
    __syncthreads();
    if (tid < 128) {
        int c = ks * 128 + tid;
        float a = b1[c];
        #pragma unroll
        for (int k = 0; k < 32; k++) a += sg[k] * W1[k * 1024 + c];
        sh[tid] = fmaxf(a, 0.0f);
    }
    __syncthreads();
    const float* w = W2 + (size_t)(ks * 128) * 512;
    float acc0 = 0.0f, acc1 = 0.0f;
    for (int k = 0; k < 128; k++) {
        float h = sh[k];
        acc0 += h * w[k * 512 + tid];
        acc1 += h * w[k * 512 + tid + 256];
    }
    atomicAdd(&h2acc[gi * 512 + tid], acc0);
    atomicAdd(&h2acc[gi * 512 + tid + 256], acc1);
}

// ---- MLP layer 3 (parallel): out[64,4] = relu(h2acc + b2) @ W3 + b3 ----
__global__ __launch_bounds__(NT) void k_mlp3p(const float* __restrict__ h2acc,
                                              const float* __restrict__ b2,
                                              const float* __restrict__ W3,
                                              const float* __restrict__ b3,
                                              float* __restrict__ out) {
    __shared__ float sp[256];
    int gi = blockIdx.x;
    int tid = threadIdx.x;
    int j = tid & 3, slot = tid >> 2;  // 64 K-slots x 4 outputs
    float part = 0.0f;
    #pragma unroll
    for (int kk = 0; kk < 8; kk++) {
        int k = slot * 8 + kk;
        float h = fmaxf(h2acc[gi * 512 + k] + b2[k], 0.0f);
        part += h * W3[k * 4 + j];
    }
    sp[tid] = part;
    __syncthreads();
    for (int s = 32; s >= 1; s >>= 1) {
        if (slot < s) sp[tid] += sp[(slot + s) * 4 + j];
        __syncthreads();
    }
    if (slot == 0) out[gi * 4 + j] = sp[j] + b3[j];
}

extern "C" void kernel_launch(void* const* d_in, const int* in_sizes, int n_in,
                              void* d_out, int out_size, void* d_ws, size_t ws_size,
                              hipStream_t stream) {
    const float* x   = (const float*)d_in[0];
    const int* ei    = (const int*)d_in[1];
    const int* batch = (const int*)d_in[2];
    const float* Wc  = (const float*)d_in[3];
    const float* bc  = (const float*)d_in[4];
    const float* W1  = (const float*)d_in[5];
    const float* b1  = (const float*)d_in[6];
    const float* W2  = (const float*)d_in[7];
    const float* b2  = (const float*)d_in[8];
    const float* W3  = (const float*)d_in[9];
    const float* b3  = (const float*)d_in[10];
    float* out       = (float*)d_out;

    const int N = in_sizes[2];      // 100000
    const int E = in_sizes[1] / 2;  // 1.6M
    const int* row = ei;
    const int* col = ei + E;
    const int NBK = (N + BSIZE - 1) / BSIZE;   // 391 (<= 512)
    const int epb = (E + HB - 1) / HB;
    const size_t PADE = (size_t)NBK * CAP;     // padded edge capacity

    // workspace layout
    float* h2acc    = (float*)d_ws;                  // 64*512 (memset)
    int* bcur       = (int*)(h2acc + 64 * 512);      // 512
    int* rcur       = bcur + 512;                    // 512
    float* dis      = (float*)(rcur + 512);          // N
    float* rdis     = dis + N;                       // N
    int* offs       = (int*)(rdis + N);              // N (+4 pad)
    int* ebuck      = offs + N + 4;                  // PADE ints
    unsigned char* rbuck = (unsigned char*)(ebuck + PADE);  // PADE bytes (4-div)
    int* entries    = (int*)(rbuck + PADE);          // PADE ints
    _Float16* xh    = (_Float16*)(entries + PADE);   // 32N halfs
    _Float16* xsh   = xh + (size_t)N * 32;           // 32N halfs
    _Float16* xs2h  = xsh + (size_t)N * 32;          // 32N halfs
    float* g        = (float*)(xs2h + (size_t)N * 32);  // 64*32
    _Float16* wfrag = (_Float16*)(g + 64 * 32);      // 6*512 halfs

    hipMemsetAsync(h2acc, 0, sizeof(float) * 64 * 512, stream);

    k_init<<<1, 512, 0, stream>>>(g, Wc, wfrag, bcur, rcur, NBK);
    k_bscatter3<<<HB, NT, 0, stream>>>(row, col, bcur, rcur, ebuck, rbuck, E, NBK, epb);
    k_prep<<<NBK, NT, 0, stream>>>(rcur, rbuck, bcur, ebuck, x, dis, rdis,
                                   (__half*)xh, (__half*)xsh, offs, entries, N);
    k_prop1<<<((size_t)N * 8 + NT - 1) / NT, NT, 0, stream>>>(offs, entries, dis, (const __half*)xsh, (__half*)xs2h, N);
    k_combine_f<<<(N + 63) / 64, NT, 0, stream>>>(offs, entries, dis, rdis, (const __half*)xs2h, xh, wfrag, bc, batch, g, N);
    k_mlp12<<<512, NT, 0, stream>>>(g, W1, b1, W2, h2acc);
    k_mlp3p<<<64, NT, 0, stream>>>(h2acc, b2, W3, b3, out);
}